// Round 10
// baseline (1590.084 us; speedup 1.0000x reference)
//
#include <hip/hip_runtime.h>

// R24: UNIT-split across 2 waves -- all 4 gates of a unit stay in one wave.
//
// 9-round synthesis: R16 (1 seq/wave, 208 wts, barrier-free) = 1058us best;
// its ledger = 437 instr/phase (~230 useful + ~200 AGPR shuttles) at 69.5%
// busy (= perfect 2-wave interleave; ~770 cyc/step uncovered stall). Every
// gate-split attempt (R18-R23) paid 2 barriers/step for the partials
// exchange and landed 1244-1555us. Ledger fix from R22/R23: VGPR grant is
// ~84; even 104 wts/wave parks ~40 in AGPRs (~40 shuttles/phase).
//
// This design needs NO partials exchange: wave owns units, not gates.
//   wave0: lanes 0-30 = I,F rows of unit L; lanes 32-62 = G,O rows of
//          unit L-32; lanes 31,63 = z-rows (W_ih2) pairs (0,1) and (2,3).
//   wave1: same layout for units 31..50 (lanes 0-19 / 32-51), z on 31,63.
// 2 rows/lane = 104 wt floats. Gates of unit u meet via IN-WAVE
// __shfl_xor(.,32) (2 ops, no barrier). z via 4 readlanes. LSTM2 computed
// REDUNDANTLY by both waves (same z -> same h2; kills cross-wave h2/c2).
// Only cross-wave dep: h1 slices -> parity-double-buffered hrow + ONE
// barrier/step. Identical instruction streams on both waves -> no skew.
// 2048 blocks x 2 waves = 4 waves/SIMD residency target.
//
// Numerics: per-row pk x/y accumulation over the same 26 k-pairs, then
// .x+.y -- bit-identical to R16 (absmax canary 0.0002441406).

#define H1N  51
#define NP   26    // k-pairs: k=0..51; k=51 slot = bias (hrow[51]=1.0)
#define NQ   13    // k-quads for the b128 hrow broadcast reads
#define WAVE 64

typedef float v2f __attribute__((ext_vector_type(2)));
typedef float v4f __attribute__((ext_vector_type(4)));

#define INV_LN2   1.44269504088896340736f
#define INV_LN2X2 2.88539008177792681472f

__device__ __forceinline__ float sigmoid_s(float xs) {   // input pre-scaled by 1/ln2
    return __builtin_amdgcn_rcpf(1.0f + __builtin_amdgcn_exp2f(-xs));
}
__device__ __forceinline__ float tanh_s2(float xs2) {    // input pre-scaled by 2/ln2
    float e = __builtin_amdgcn_exp2f(xs2);
    return fmaf(-2.0f, __builtin_amdgcn_rcpf(e + 1.0f), 1.0f);
}
__device__ __forceinline__ float tanh_nat(float x) {
    return tanh_s2(x * INV_LN2X2);
}
__device__ __forceinline__ float rdlane(float v, int k) {
    return __int_as_float(__builtin_amdgcn_readlane(__float_as_int(v), k));
}

__global__ __attribute__((amdgpu_flat_work_group_size(128, 128),
                          amdgpu_waves_per_eu(2)))
void lstm_us(const float* __restrict__ input,   // [B, T]
             const float* __restrict__ W_ih1,   // [204, 1]
             const float* __restrict__ W_hh1,   // [204, 51]
             const float* __restrict__ b_ih1,   // [204]
             const float* __restrict__ b_hh1,   // [204]
             const float* __restrict__ W_ih2,   // [4, 51]
             const float* __restrict__ W_hh2,   // [4, 1]
             const float* __restrict__ b_ih2,   // [4]
             const float* __restrict__ b_hh2,   // [4]
             float* __restrict__ out,           // [B, T+F]
             int T, int TF)
{
    const int tid  = threadIdx.x;
    const int j    = tid & (WAVE - 1);
    const int wid  = tid >> 6;                  // wave: 0 = units 0..30, 1 = 31..50
    const bool w0  = (wid == 0);
    const int half = j >> 5;                    // 0: I,F rows   1: G,O rows
    const bool hb_ = (half != 0);
    const int l5   = j & 31;

    const int nU = w0 ? 31 : 20;                // units this wave owns
    const int u0 = w0 ? 0 : 31;
    const bool uv = (l5 < nU);                  // unit-lane valid
    const int unit = u0 + (uv ? l5 : 0);        // clamped
    const float mU = uv ? 1.0f : 0.0f;
    const bool isZ = (l5 == 31);                // z-row lane (both halves)
    const float mZ = isZ ? 1.0f : 0.0f;

    // Rows this lane holds: A = I or G, B = F or O (of `unit`).
    const int rA = (half ? 2*H1N : 0)   + unit;
    const int rB = (half ? 3*H1N : H1N) + unit;
    const float sclA = half ? INV_LN2X2 : INV_LN2;  // G is the tanh gate
    const float sclB = INV_LN2;
    const int qA = half ? 2 : 0;                // z rows: (0,1) / (2,3)
    const int qB = half ? 3 : 1;
    // z scale == sclA/sclB per half (q=2 is LSTM2's tanh gate). Verified:
    // half0: q0,q1 -> 1/ln2,1/ln2 = sclA,sclB; half1: q2,q3 -> X2,1 = sclA,sclB.

    __shared__ __align__(16) float hrow[2][WAVE];   // [par][slot]; slot 51 = bias 1.0

    // 104 weight floats (52 v2f). Bias folded into the k=51 slot
    // (hrow[51]==1.0); z-lanes carry W_ih2 rows, zero bias slot.
    v2f wA[NP], wB[NP];
#pragma unroll
    for (int kk = 0; kk < NP; ++kk) {
        const int k0 = 2*kk, k1 = k0 + 1;
        wA[kk].x = mU*sclA*W_hh1[rA*H1N + k0] + mZ*sclA*W_ih2[qA*H1N + k0];
        wB[kk].x = mU*sclB*W_hh1[rB*H1N + k0] + mZ*sclB*W_ih2[qB*H1N + k0];
        if (k1 < H1N) {
            wA[kk].y = mU*sclA*W_hh1[rA*H1N + k1] + mZ*sclA*W_ih2[qA*H1N + k1];
            wB[kk].y = mU*sclB*W_hh1[rB*H1N + k1] + mZ*sclB*W_ih2[qB*H1N + k1];
        } else {   // k1 == 51: bias slot; z-rows get 0
            wA[kk].y = mU*sclA*(b_ih1[rA] + b_hh1[rA]);
            wB[kk].y = mU*sclB*(b_ih1[rB] + b_hh1[rB]);
        }
    }
#pragma unroll
    for (int kk = 0; kk < NP; ++kk)
        asm volatile("" : "+v"(wA[kk]), "+v"(wB[kk]));   // pin: no remat

    // x-side weights for this lane's UNIT (all 4 gates -- cell update is
    // computed on every lane for its unit after the shfl).
    const float wx_i = mU*INV_LN2  *W_ih1[unit];
    const float wx_f = mU*INV_LN2  *W_ih1[H1N + unit];
    const float wx_g = mU*INV_LN2X2*W_ih1[2*H1N + unit];
    const float wx_o = mU*INV_LN2  *W_ih1[3*H1N + unit];

    // LSTM2 thread-uniform scalars (SGPRs), pre-scaled.
    const float wh2_0 = INV_LN2*W_hh2[0], wh2_1 = INV_LN2*W_hh2[1];
    const float wh2_2 = INV_LN2X2*W_hh2[2], wh2_3 = INV_LN2*W_hh2[3];
    const float b2_0 = INV_LN2*(b_ih2[0] + b_hh2[0]), b2_1 = INV_LN2*(b_ih2[1] + b_hh2[1]);
    const float b2_2 = INV_LN2X2*(b_ih2[2] + b_hh2[2]), b2_3 = INV_LN2*(b_ih2[3] + b_hh2[3]);

    // Init both parities: h1(-1)=0; slot 51 = 1.0 (bias, never rewritten).
    if (w0) {
        const float e = (j == H1N) ? 1.0f : 0.0f;
        hrow[0][j] = e;
        hrow[1][j] = e;
    }
    __syncthreads();

    const int s = blockIdx.x;                   // one sequence per block
    const float* __restrict__ xrow = input + (long)s * T;
    float* __restrict__ orow = out + (long)s * TF;

    float c1 = 0.0f, h2 = 0.0f, c2 = 0.0f, obuf = 0.0f, xbuf = 0.0f;
    int par = 0;                                // matvec(t) reads hrow[par]

    const bool jw = (half == 0) && uv;          // h1 writer mask (one lane/unit)

    // Phase t: matvec(h1(t-1)) -> [LSTM2(t-1)] -> [LSTM1 cell(t)] ->
    // barrier -> flip parity. Flags compile-time at every call site.
    auto PH = [&](int t, int xmode, int do_l2, int do_fin) {
        const float* __restrict__ hbp = &hrow[par][0];
        v2f aA = {0.0f, 0.0f}, aB = {0.0f, 0.0f};
#pragma unroll
        for (int kq = 0; kq < NQ; ++kq) {
            const v4f h4 = *(const v4f*)&hbp[4*kq];       // ds_read_b128 bcast
            const v2f hp0 = __builtin_shufflevector(h4, h4, 0, 1);
            const v2f hp1 = __builtin_shufflevector(h4, h4, 2, 3);
            asm("v_pk_fma_f32 %0, %2, %4, %0\n\t"
                "v_pk_fma_f32 %1, %3, %4, %1"
                : "+v"(aA), "+v"(aB)
                : "v"(wA[2*kq]), "v"(wB[2*kq]), "v"(hp0));
            asm("v_pk_fma_f32 %0, %2, %4, %0\n\t"
                "v_pk_fma_f32 %1, %3, %4, %1"
                : "+v"(aA), "+v"(aB)
                : "v"(wA[2*kq+1]), "v"(wB[2*kq+1]), "v"(hp1));
        }
        const float sAp = aA.x + aA.y;          // my row A dot (I or G, or z)
        const float sBp = aB.x + aB.y;          // my row B dot (F or O, or z)

        if (do_l2) {                            // LSTM2 step t-1 (redundant
            const float z0 = rdlane(sAp, 31);   //  on both waves; identical)
            const float z1 = rdlane(sBp, 31);
            const float z2 = rdlane(sAp, 63);
            const float z3 = rdlane(sBp, 63);
            const float g2i = sigmoid_s(fmaf(wh2_0, h2, b2_0 + z0));
            const float g2f = sigmoid_s(fmaf(wh2_1, h2, b2_1 + z1));
            const float g2g = tanh_s2 (fmaf(wh2_2, h2, b2_2 + z2));
            const float g2o = sigmoid_s(fmaf(wh2_3, h2, b2_3 + z3));
            c2 = fmaf(g2f, c2, g2i * g2g);
            h2 = g2o * tanh_nat(c2);
            obuf = (j == ((t - 1) & 63)) ? h2 : obuf;     // pack out(t-1)
            if ((t & 63) == 0) {                          // flush t-64..t-1
                if (w0) orow[t - 64 + j] = obuf;
            }
        }
        if (do_fin) {                           // LSTM1 cell(t) for my unit
            // Bring the partner half's row dots in-wave: no barrier.
            const float swA = __shfl_xor(sAp, 32);
            const float swB = __shfl_xor(sBp, 32);
            const float mI = hb_ ? swA : sAp;
            const float mF = hb_ ? swB : sBp;
            const float mG = hb_ ? sAp : swA;
            const float mO = hb_ ? sBp : swB;

            float x;
            if (xmode == 0) {
                if ((t & 63) == 0) xbuf = xrow[t + j];
                x = rdlane(xbuf, t & 63);
            } else {
                x = h2;                         // feedback (h2(t-1), fresh)
            }
            const float gi = sigmoid_s(fmaf(wx_i, x, mI));
            const float gf = sigmoid_s(fmaf(wx_f, x, mF));
            const float gg = tanh_s2 (fmaf(wx_g, x, mG));
            const float go = sigmoid_s(fmaf(wx_o, x, mO));
            c1 = fmaf(gf, c1, gi * gg);
            const float h1 = go * tanh_nat(c1);
            if (jw) hrow[par ^ 1][unit] = h1;   // publish my unit's h1(t)
        }
        __syncthreads();                        // the ONE barrier per step
        par ^= 1;
    };

    // ---- t=0: cell(0) only (matvec of h(-1)=0; z garbage unused) ----
    PH(0, 0, 0, 1);

    // ---- warm: t = 1..T-1 (x from input) ----
    for (int t = 1; t < T; ++t)
        PH(t, 0, 1, 1);

    // ---- boundary: t = T (LSTM2(T-1); first feedback cell x=h2) ----
    PH(T, 1, 1, 1);

    // ---- future: t = T+1..TF-1 (x = h2 feedback) ----
    for (int t = T + 1; t < TF; ++t)
        PH(t, 1, 1, 1);

    // ---- drain: t = TF (LSTM2(TF-1) + final flush; no cell) ----
    PH(TF, 1, 1, 0);
}

extern "C" void kernel_launch(void* const* d_in, const int* in_sizes, int n_in,
                              void* d_out, int out_size, void* d_ws, size_t ws_size,
                              hipStream_t stream) {
    const float* input = (const float*)d_in[0];
    const float* W_ih1 = (const float*)d_in[1];
    const float* W_hh1 = (const float*)d_in[2];
    const float* b_ih1 = (const float*)d_in[3];
    const float* b_hh1 = (const float*)d_in[4];
    const float* W_ih2 = (const float*)d_in[5];
    const float* W_hh2 = (const float*)d_in[6];
    const float* b_ih2 = (const float*)d_in[7];
    const float* b_hh2 = (const float*)d_in[8];
    float* out = (float*)d_out;

    const int B  = 2048;
    const int T  = in_sizes[0] / B;      // 1024
    const int TF = out_size   / B;       // 1088

    lstm_us<<<dim3(B), dim3(2 * WAVE), 0, stream>>>(
        input, W_ih1, W_hh1, b_ih1, b_hh1, W_ih2, W_hh2, b_ih2, b_hh2,
        out, T, TF);
}